// Round 7
// baseline (382.542 us; speedup 1.0000x reference)
//
#include <hip/hip_runtime.h>

#define N_NODES 100000
#define G_NODES 50000
#define N_EDGES 800000
#define H 64
#define F_IN 32
#define MAX_DEG 20
#define NUM_GRAPHS 128
#define LN_EPS 1e-5f
#define POOL_BLOCKS 96
#define MAX_TILES 1600

// Binned CSR build: 512 bins over the 4*N key space, FIXED 8192-entry
// capacity per bin (mean 6250, sigma~79 -> +24 sigma, unreachable).
#define NBINS 512
#define BPB 782            // keys per bin: 782*512 = 400384 >= 400000
#define BINCAP_LOG 13      // 8192 entries per bin
#define BINCAP 8192
#define CHUNK 6250         // edges per build block: 6250*512 = 3.2M
#define MKEYS (4 * N_NODES)
#define MEDGES (4 * N_EDGES)

#define WCONV_BLOCKS 2688  // 84*64*128/256
#define EMB_BLOCKS 1563    // ceil(N_NODES/64)

typedef __attribute__((ext_vector_type(8))) short short8;
typedef __attribute__((ext_vector_type(4))) float float4v;

// bf16 helpers (RNE), no header dependency
static __device__ __forceinline__ unsigned short f2b(float f) {
  unsigned u = __float_as_uint(f);
  return (unsigned short)((u + 0x7fffu + ((u >> 16) & 1u)) >> 16);
}
static __device__ __forceinline__ float b2f(unsigned short b) {
  return __uint_as_float(((unsigned)b) << 16);
}

// ------- R7: fused weight-preconvert + cursor init + MFMA embedding ---------
// wconv branch (bid < WCONV_BLOCKS) and emb branch are INDEPENDENT (emb
// converts emb_w inline from the 8KB L1-resident table instead of reading
// ewbt -> no intra-dispatch race). 12 -> 10 dispatches.
__global__ __launch_bounds__(256) void prep_kernel(
    const float* __restrict__ wl, const float* __restrict__ wr,
    const float* __restrict__ ew, unsigned short* __restrict__ wbt,
    unsigned short* __restrict__ ewbt, int* __restrict__ bincur,
    int* __restrict__ bcnt,
    const float* __restrict__ x, const float* __restrict__ eb,
    float* __restrict__ h0, unsigned short* __restrict__ ab,
    float* __restrict__ pooled) {
  int bid = blockIdx.x;
  int tid = threadIdx.x;
  if (bid < WCONV_BLOCKS) {
    int i = bid * 256 + tid;
    if (bid == 0) {
      for (int k = tid; k < NBINS; k += 256) bincur[k] = k << BINCAP_LOG;
      if (tid < 84) bcnt[tid] = 0;
    }
    if (i < 84 * 64 * 128) {
      int k = i & 127;
      int ch = (i >> 7) & 63;
      int jb = i >> 13;
      float v = (k < 64) ? wl[jb * 4096 + k * 64 + ch]
                         : wr[jb * 4096 + (k - 64) * 64 + ch];
      wbt[i] = f2b(v);
    } else if (i < 84 * 64 * 128 + H * F_IN) {
      int ii = i - 84 * 64 * 128;
      int c = ii >> 5, f = ii & 31;
      ewbt[ii] = f2b(ew[f * H + c]);
    }
    return;
  }
  // ---- emb branch ----
  int ebid = bid - WCONV_BLOCKS;
  if (ebid == 0) {
    for (int i = tid; i < NUM_GRAPHS * H; i += 256) pooled[i] = 0.f;
  }
  int base = ebid * 64;
  int nIn = min(64, N_NODES - base);
  int qw = tid >> 6, lane = tid & 63;
  __shared__ unsigned short aL[64 * 40];  // stride 40 breaks pow2 banks
  __shared__ float outF[64 * 68];

  {
    int node = tid >> 2, chb = (tid & 3) * 8;
    unsigned short v8[8];
    if (node < nIn) {
      const float* xr = x + ((size_t)(base + node)) * F_IN + chb;
      float4 f0 = *(const float4*)(xr);
      float4 f1 = *(const float4*)(xr + 4);
      v8[0] = f2b(f0.x); v8[1] = f2b(f0.y); v8[2] = f2b(f0.z); v8[3] = f2b(f0.w);
      v8[4] = f2b(f1.x); v8[5] = f2b(f1.y); v8[6] = f2b(f1.z); v8[7] = f2b(f1.w);
    } else {
#pragma unroll
      for (int i = 0; i < 8; ++i) v8[i] = 0;
    }
    *(short8*)&aL[(tid >> 2) * 40 + chb] = *(short8*)v8;
  }
  // no __syncthreads: wave qw staged exactly rows [qw*16, qw*16+16)

  int m = lane & 15, quad = lane >> 4;
  short8 a = *(const short8*)&aL[(qw * 16 + m) * 40 + quad * 8];
  float4v acc[4];
#pragma unroll
  for (int t = 0; t < 4; ++t) {
    float bv = eb[t * 16 + m];
    acc[t] = (float4v){bv, bv, bv, bv};
  }
#pragma unroll
  for (int t = 0; t < 4; ++t) {
    // inline B-fragment: f2b(ew[f*H + c]), c = t*16+m, f = quad*8..+7
    unsigned short bfv[8];
#pragma unroll
    for (int f = 0; f < 8; ++f) bfv[f] = f2b(ew[(quad * 8 + f) * H + t * 16 + m]);
    short8 bf = *(short8*)bfv;
    acc[t] = __builtin_amdgcn_mfma_f32_16x16x32_bf16(a, bf, acc[t], 0, 0, 0);
  }
#pragma unroll
  for (int t = 0; t < 4; ++t)
#pragma unroll
    for (int r = 0; r < 4; ++r)
      outF[(qw * 16 + quad * 4 + r) * 68 + t * 16 + m] = acc[t][r];
  for (int r = qw * 16; r < qw * 16 + 16; ++r) {
    if (r < nIn) {
      int node = base + r;
      float v = outF[r * 68 + lane];
      if (node < G_NODES) h0[node * H + lane] = v;
      ab[node * 128 + 64 + lane] = f2b(v);
    }
  }
}

// ---------------- single-pass binning + LDS bin-sort (R5) -------------------
__global__ __launch_bounds__(1024) void p3_binscatter(
    const int* __restrict__ e0, const int* __restrict__ e1,
    const int* __restrict__ e2, const int* __restrict__ e3,
    int* __restrict__ bincur, unsigned* __restrict__ binned) {
  __shared__ int hist[NBINS];
  __shared__ int loff[NBINS];
  __shared__ int gcur[NBINS];
  __shared__ int lcur[NBINS];
  __shared__ int wtot[16];
  __shared__ int lmeta[CHUNK];            // (bin<<10)|keymod per edge, 25 KB
  __shared__ unsigned sbuf[CHUNK];        // staged values, 25 KB
  __shared__ unsigned short sbin[CHUNK];  // bin per staged entry, 12.5 KB
  int t = threadIdx.x, b = blockIdx.x;
  for (int i = t; i < NBINS; i += 1024) hist[i] = 0;
  __syncthreads();
  int j = b >> 7;
  const int* ei = (j == 0) ? e0 : (j == 1) ? e1 : (j == 2) ? e2 : e3;
  int ebase = (b & 127) * CHUNK;
  for (int i = t; i < CHUNK; i += 1024) {
    int dst = ei[N_EDGES + ebase + i];
    int key = j * N_NODES + dst;
    int bin = key / BPB;                  // magic-mul
    lmeta[i] = (bin << 10) | (key - bin * BPB);
    atomicAdd(&hist[bin], 1);
  }
  __syncthreads();
  // exclusive scan over 512 bins (waves 0..7)
  int v = (t < NBINS) ? hist[t] : 0;
  int incl = v;
#pragma unroll
  for (int off = 1; off < 64; off <<= 1) {
    int y = __shfl_up(incl, off, 64);
    if ((t & 63) >= off) incl += y;
  }
  if (t < NBINS && (t & 63) == 63) wtot[t >> 6] = incl;
  __syncthreads();
  if (t < NBINS) {
    int wbase = 0;
    for (int w = 0; w < (t >> 6); ++w) wbase += wtot[w];
    int ex = wbase + incl - v;
    loff[t] = ex;
    lcur[t] = ex;
    gcur[t] = v ? atomicAdd(&bincur[t], v) : 0;
  }
  __syncthreads();
  for (int i = t; i < CHUNK; i += 1024) {
    int src = ei[ebase + i];
    int m = lmeta[i];
    int bin = m >> 10;
    int pos = atomicAdd(&lcur[bin], 1);
    sbuf[pos] = ((unsigned)(m & 1023) << 17) | (unsigned)src;
    sbin[pos] = (unsigned short)bin;
  }
  __syncthreads();
  for (int i = t; i < CHUNK; i += 1024) {
    int bb = sbin[i];
    binned[gcur[bb] + (i - loff[bb])] = sbuf[i];
  }
}

// p46: per bin, fused deg4 + bucket-hist + local CSR scan + slot scatter.
// R4: slot scatter staged in LDS, dense flush. R5: input staged in LDS too.
__global__ __launch_bounds__(1024) void p46_kernel(
    const unsigned* __restrict__ binned, const int* __restrict__ bincur,
    int* __restrict__ deg4, int* __restrict__ S, int* __restrict__ slots,
    int* __restrict__ bcnt) {
  __shared__ int hist[BPB];
  __shared__ int cur[BPB];
  __shared__ int bh[84];
  __shared__ int wtot[16];
  __shared__ unsigned bufin[BINCAP];   // 32 KB input staging
  __shared__ int bufout[BINCAP];       // 32 KB slot staging
  int t = threadIdx.x, bin = blockIdx.x;
  int kb = bin * BPB;
  for (int i = t; i < BPB; i += 1024) hist[i] = 0;
  if (t < 84) bh[t] = 0;
  __syncthreads();
  int start = bin << BINCAP_LOG;
  int end = bincur[bin];
  int n = end - start;
  for (int i = t; i < n; i += 1024) {
    unsigned v = binned[start + i];
    bufin[i] = v;
    atomicAdd(&hist[v >> 17], 1);
  }
  __syncthreads();
  for (int i = t; i < BPB; i += 1024) {
    int key = kb + i;
    if (key < MKEYS) {
      int d = hist[i];
      deg4[key] = d;
      int j = key / N_NODES;
      int b = d < MAX_DEG ? d : MAX_DEG;
      atomicAdd(&bh[j * 21 + b], 1);
    }
  }
  int base = t * 4;
  int v0 = 0, v1 = 0, v2 = 0, v3 = 0;
  if (base < BPB) {
    v0 = hist[base];
    v1 = (base + 1 < BPB) ? hist[base + 1] : 0;
    v2 = (base + 2 < BPB) ? hist[base + 2] : 0;
    v3 = (base + 3 < BPB) ? hist[base + 3] : 0;
  }
  int s = v0 + v1 + v2 + v3;
  int incl = s;
#pragma unroll
  for (int off = 1; off < 64; off <<= 1) {
    int y = __shfl_up(incl, off, 64);
    if ((t & 63) >= off) incl += y;
  }
  if ((t & 63) == 63) wtot[t >> 6] = incl;
  __syncthreads();
  int wbase = 0;
  for (int w = 0; w < (t >> 6); ++w) wbase += wtot[w];
  int ex = wbase + incl - s;           // bin-LOCAL exclusive prefix
  if (base < BPB) {
    cur[base] = ex;
    if (base + 1 < BPB) cur[base + 1] = ex + v0;
    if (base + 2 < BPB) cur[base + 2] = ex + v0 + v1;
    if (base + 3 < BPB) cur[base + 3] = ex + v0 + v1 + v2;
  }
  __syncthreads();
  for (int i = t; i < BPB; i += 1024)
    if (kb + i < MKEYS) S[kb + i] = start + cur[i];
  if (t < 84 && bh[t]) atomicAdd(&bcnt[t], bh[t]);
  __syncthreads();
  for (int i = t; i < n; i += 1024) {
    unsigned v = bufin[i];
    int pos = atomicAdd(&cur[v >> 17], 1);   // LDS scatter (bin-local pos)
    bufout[pos] = (int)(v & 0x1ffffu);
  }
  __syncthreads();
  for (int i = t; i < n; i += 1024) slots[start + i] = bufout[i];  // dense flush
}

// ---------------- bucket scan + tile descriptors (one block) ----------------
__global__ __launch_bounds__(128) void bucket_scan(
    const int* __restrict__ bcnt, int* __restrict__ boff, int* __restrict__ bcur,
    int* __restrict__ ntiles, int* __restrict__ tdesc) {
  __shared__ int wt[2];
  __shared__ int exL[84], cntL[84], toffL[84];
  int t = threadIdx.x;
  int v = (t < 84) ? bcnt[t] : 0;
  int incl = v;
#pragma unroll
  for (int off = 1; off < 64; off <<= 1) {
    int y = __shfl_up(incl, off, 64);
    if ((t & 63) >= off) incl += y;
  }
  if ((t & 63) == 63) wt[t >> 6] = incl;
  __syncthreads();
  int wbase = (t >> 6) ? wt[0] : 0;
  if (t < 84) {
    int ex = wbase + incl - v;
    boff[t] = ex;
    bcur[t] = ex;
    exL[t] = ex;
    cntL[t] = v;
  }
  __syncthreads();
  if (t < 4) {
    int acc = 0;
    for (int bb = 0; bb < 21; ++bb) {
      toffL[t * 21 + bb] = acc;
      acc += (cntL[t * 21 + bb] + 63) >> 6;
    }
    ntiles[t] = acc;
  }
  __syncthreads();
  for (int jb = 0; jb < 84; ++jb) {
    int j = jb / 21, b = jb - j * 21;
    int cnt = cntL[jb], off = exL[jb], tb = toffL[jb];
    int nt = (cnt + 63) >> 6;
    for (int i = t; i < nt; i += 128) {
      int s2 = i << 6;
      int nIn = min(64, cnt - s2);
      tdesc[j * MAX_TILES + tb + i] = ((off + s2) << 12) | (b << 7) | nIn;
    }
  }
}

__global__ __launch_bounds__(256) void bucket_fill(
    const int* __restrict__ deg4, int* __restrict__ bcur, int* __restrict__ blist) {
  __shared__ int hist[21];
  __shared__ int base[21];
  int t = threadIdx.x;
  if (t < 21) hist[t] = 0;
  __syncthreads();
  int node = blockIdx.x * 256 + t;
  int j = blockIdx.y;
  int b = 0, lpos = 0;
  bool valid = (node < N_NODES);
  if (valid) {
    int d = deg4[j * N_NODES + node];
    b = d < MAX_DEG ? d : MAX_DEG;
    lpos = atomicAdd(&hist[b], 1);
  }
  __syncthreads();
  if (t < 21 && hist[t]) base[t] = atomicAdd(&bcur[j * 21 + t], hist[t]);
  __syncthreads();
  if (valid) blist[base[b] + lpos] = node;
}

// ---------------- FUSED conv: lane-per-row-slice gather + MFMA --------------
// R2: lane-per-row-slice: row = tid>>2, each lane owns 16 channels (32B) of
// ONE row; all 64 rows gather concurrently. R7: e-loop unroll 4->8 (16
// dwordx4 in flight per lane) -> latency rounds = ceil(deg/8).
__global__ __launch_bounds__(256) void conv_kernel(
    float* __restrict__ h, unsigned short* __restrict__ ab,
    const int* __restrict__ S, const int* __restrict__ deg,
    const int* __restrict__ slots,
    const int* __restrict__ blist, const int* __restrict__ tdesc,
    const int* __restrict__ ntiles, const unsigned short* __restrict__ wbt,
    const float* __restrict__ bl, int j, int inoff, int do_relu, int last) {
  if ((int)blockIdx.x >= ntiles[j]) return;
  int d = tdesc[j * MAX_TILES + blockIdx.x];
  int nIn = d & 127;
  int b = (d >> 7) & 31;
  const int* lst = blist + (d >> 12);
  int outoff = 64 - inoff;

  int tid = threadIdx.x;
  int qw = tid >> 6, lane = tid & 63;

  if (b == 0) {
    for (int r = qw * 16; r < qw * 16 + 16; ++r) {
      if (r < nIn) {
        int node = lst[r];
        float v = b2f(ab[node * 128 + inoff + lane]);
        if (do_relu) v = fmaxf(v, 0.f);
        if (last) {
          if (node < G_NODES) h[node * H + lane] = v;
        } else {
          ab[node * 128 + outoff + lane] = f2b(v);
        }
      }
    }
    return;
  }

  __shared__ unsigned short aL[64 * 136];  // 17408 B; reused as fp32[64*68]
  __shared__ int nodeS[64];

  {
    int r = tid >> 2;            // row 0..63 (wave qw owns rows qw*16..+15)
    int cb = (tid & 3) * 16;     // 16-channel slice (32B) within the row
    bool act = (r < nIn);
    int node = act ? lst[r] : 0;
    if ((tid & 3) == 0 && act) nodeS[r] = node;

    float acc[16];
#pragma unroll
    for (int k = 0; k < 16; ++k) acc[k] = 0.f;
    uint4 selfA = make_uint4(0u, 0u, 0u, 0u);
    uint4 selfB = make_uint4(0u, 0u, 0u, 0u);

#define ACC8(v, kb)                                                      \
  acc[kb + 0] += b2f((unsigned short)(v).x);                             \
  acc[kb + 1] += b2f((unsigned short)((v).x >> 16));                     \
  acc[kb + 2] += b2f((unsigned short)(v).y);                             \
  acc[kb + 3] += b2f((unsigned short)((v).y >> 16));                     \
  acc[kb + 4] += b2f((unsigned short)(v).z);                             \
  acc[kb + 5] += b2f((unsigned short)((v).z >> 16));                     \
  acc[kb + 6] += b2f((unsigned short)(v).w);                             \
  acc[kb + 7] += b2f((unsigned short)((v).w >> 16));

    if (act) {
      const unsigned short* abb = ab + inoff + cb;
      selfA = *(const uint4*)&abb[node * 128];
      selfB = *(const uint4*)&abb[node * 128 + 8];
      int off = S[node];
      int dg = (b < MAX_DEG) ? b : deg[node];
      int e = 0;
      for (; e + 7 < dg; e += 8) {
        int n0 = slots[off + e];
        int n1 = slots[off + e + 1];
        int n2 = slots[off + e + 2];
        int n3 = slots[off + e + 3];
        int n4 = slots[off + e + 4];
        int n5 = slots[off + e + 5];
        int n6 = slots[off + e + 6];
        int n7 = slots[off + e + 7];
        uint4 a0 = *(const uint4*)&abb[n0 * 128];
        uint4 b0 = *(const uint4*)&abb[n0 * 128 + 8];
        uint4 a1 = *(const uint4*)&abb[n1 * 128];
        uint4 b1 = *(const uint4*)&abb[n1 * 128 + 8];
        uint4 a2 = *(const uint4*)&abb[n2 * 128];
        uint4 b2 = *(const uint4*)&abb[n2 * 128 + 8];
        uint4 a3 = *(const uint4*)&abb[n3 * 128];
        uint4 b3 = *(const uint4*)&abb[n3 * 128 + 8];
        uint4 a4 = *(const uint4*)&abb[n4 * 128];
        uint4 b4 = *(const uint4*)&abb[n4 * 128 + 8];
        uint4 a5 = *(const uint4*)&abb[n5 * 128];
        uint4 b5 = *(const uint4*)&abb[n5 * 128 + 8];
        uint4 a6 = *(const uint4*)&abb[n6 * 128];
        uint4 b6 = *(const uint4*)&abb[n6 * 128 + 8];
        uint4 a7 = *(const uint4*)&abb[n7 * 128];
        uint4 b7 = *(const uint4*)&abb[n7 * 128 + 8];
        ACC8(a0, 0) ACC8(b0, 8)
        ACC8(a1, 0) ACC8(b1, 8)
        ACC8(a2, 0) ACC8(b2, 8)
        ACC8(a3, 0) ACC8(b3, 8)
        ACC8(a4, 0) ACC8(b4, 8)
        ACC8(a5, 0) ACC8(b5, 8)
        ACC8(a6, 0) ACC8(b6, 8)
        ACC8(a7, 0) ACC8(b7, 8)
      }
      for (; e + 3 < dg; e += 4) {
        int n0 = slots[off + e];
        int n1 = slots[off + e + 1];
        int n2 = slots[off + e + 2];
        int n3 = slots[off + e + 3];
        uint4 a0 = *(const uint4*)&abb[n0 * 128];
        uint4 b0 = *(const uint4*)&abb[n0 * 128 + 8];
        uint4 a1 = *(const uint4*)&abb[n1 * 128];
        uint4 b1 = *(const uint4*)&abb[n1 * 128 + 8];
        uint4 a2 = *(const uint4*)&abb[n2 * 128];
        uint4 b2 = *(const uint4*)&abb[n2 * 128 + 8];
        uint4 a3 = *(const uint4*)&abb[n3 * 128];
        uint4 b3 = *(const uint4*)&abb[n3 * 128 + 8];
        ACC8(a0, 0) ACC8(b0, 8)
        ACC8(a1, 0) ACC8(b1, 8)
        ACC8(a2, 0) ACC8(b2, 8)
        ACC8(a3, 0) ACC8(b3, 8)
      }
      int rem = dg - e;
      if (rem > 0) {
        int n0 = slots[off + e];
        int n1 = (rem > 1) ? slots[off + e + 1] : n0;
        int n2 = (rem > 2) ? slots[off + e + 2] : n0;
        uint4 a0 = *(const uint4*)&abb[n0 * 128];
        uint4 b0 = *(const uint4*)&abb[n0 * 128 + 8];
        uint4 a1 = *(const uint4*)&abb[n1 * 128];
        uint4 b1 = *(const uint4*)&abb[n1 * 128 + 8];
        uint4 a2 = *(const uint4*)&abb[n2 * 128];
        uint4 b2 = *(const uint4*)&abb[n2 * 128 + 8];
        ACC8(a0, 0) ACC8(b0, 8)
        if (rem > 1) { ACC8(a1, 0) ACC8(b1, 8) }
        if (rem > 2) { ACC8(a2, 0) ACC8(b2, 8) }
      }
    }
#undef ACC8

    unsigned p0 = (unsigned)f2b(acc[0]) | ((unsigned)f2b(acc[1]) << 16);
    unsigned p1 = (unsigned)f2b(acc[2]) | ((unsigned)f2b(acc[3]) << 16);
    unsigned p2 = (unsigned)f2b(acc[4]) | ((unsigned)f2b(acc[5]) << 16);
    unsigned p3 = (unsigned)f2b(acc[6]) | ((unsigned)f2b(acc[7]) << 16);
    unsigned p4 = (unsigned)f2b(acc[8]) | ((unsigned)f2b(acc[9]) << 16);
    unsigned p5 = (unsigned)f2b(acc[10]) | ((unsigned)f2b(acc[11]) << 16);
    unsigned p6 = (unsigned)f2b(acc[12]) | ((unsigned)f2b(acc[13]) << 16);
    unsigned p7 = (unsigned)f2b(acc[14]) | ((unsigned)f2b(acc[15]) << 16);
    *(uint4*)&aL[r * 136 + cb] = make_uint4(p0, p1, p2, p3);       // hsum k 0:64
    *(uint4*)&aL[r * 136 + cb + 8] = make_uint4(p4, p5, p6, p7);
    *(uint4*)&aL[r * 136 + 64 + cb] = selfA;                       // self k 64:128
    *(uint4*)&aL[r * 136 + 64 + cb + 8] = selfB;
  }
  // no barrier: wave wrote exactly rows [qw*16, qw*16+16) and reads only those

  int m = lane & 15, quad = lane >> 4;
  const unsigned short* wbase = wbt + (size_t)(j * 21 + b) * 64 * 128;
  float4v acc[4];
#pragma unroll
  for (int t = 0; t < 4; ++t) {
    float bv = bl[b * 64 + t * 16 + m];
    acc[t] = (float4v){bv, bv, bv, bv};
  }
#pragma unroll
  for (int ks = 0; ks < 4; ++ks) {
    short8 a = *(const short8*)&aL[(qw * 16 + m) * 136 + ks * 32 + quad * 8];
#pragma unroll
    for (int t = 0; t < 4; ++t) {
      short8 bf = *(const short8*)&wbase[(t * 16 + m) * 128 + ks * 32 + quad * 8];
      acc[t] = __builtin_amdgcn_mfma_f32_16x16x32_bf16(a, bf, acc[t], 0, 0, 0);
    }
  }
  if (do_relu) {
#pragma unroll
    for (int t = 0; t < 4; ++t)
#pragma unroll
      for (int r = 0; r < 4; ++r) acc[t][r] = fmaxf(acc[t][r], 0.f);
  }
  float* outF = (float*)aL;
#pragma unroll
  for (int t = 0; t < 4; ++t)
#pragma unroll
    for (int r = 0; r < 4; ++r)
      outF[(qw * 16 + quad * 4 + r) * 68 + t * 16 + m] = acc[t][r];
  if (last) {
    for (int r = qw * 16; r < qw * 16 + 16; ++r)
      if (r < nIn && nodeS[r] < G_NODES)
        h[nodeS[r] * H + lane] = outF[r * 68 + lane];
  } else {
    for (int r = qw * 16; r < qw * 16 + 16; ++r)
      if (r < nIn) ab[nodeS[r] * 128 + outoff + lane] = f2b(outF[r * 68 + lane]);
  }
}

// ---------------- fused layernorm + residual + ground-node pool -------------
// R17+R3 lesson: no cross-grid fences. R7: POOL_BLOCKS 256->96 cuts the
// global pooled atomic flush from 2.0M to 0.79M L2 RMWs.
__global__ __launch_bounds__(1024) void ln_pool_kernel(
    const float* __restrict__ h, const float* __restrict__ h0,
    const float* __restrict__ g, const float* __restrict__ b,
    const int* __restrict__ batch, float* __restrict__ pooled) {
  __shared__ float sm[NUM_GRAPHS * H];  // 32 KB
  int t = threadIdx.x;
  for (int i = t; i < NUM_GRAPHS * H; i += 1024) sm[i] = 0.f;
  __syncthreads();
  int lane = t & 63, w = t >> 6;  // 16 waves
  const int per = (G_NODES + POOL_BLOCKS - 1) / POOL_BLOCKS;
  int start = blockIdx.x * per;
  int end = min(start + per, G_NODES);
  for (int node = start + w; node < end; node += 16) {
    int idx = node * H + lane;
    float v = h[idx];
    float s = v;
#pragma unroll
    for (int off = 32; off > 0; off >>= 1) s += __shfl_xor(s, off, 64);
    float mu = s * (1.0f / H);
    float dv = v - mu;
    float q = dv * dv;
#pragma unroll
    for (int off = 32; off > 0; off >>= 1) q += __shfl_xor(q, off, 64);
    float inv = rsqrtf(q * (1.0f / H) + LN_EPS);
    float r = dv * inv * g[lane] + b[lane] + h0[idx];
    atomicAdd(&sm[batch[node] * H + lane], r);
  }
  __syncthreads();
  for (int i = t; i < NUM_GRAPHS * H; i += 1024) {
    float v = sm[i];
    if (v != 0.f) atomicAdd(&pooled[i], v);
  }
}

__global__ __launch_bounds__(64) void out_kernel(
    const float* __restrict__ pooled, const float* __restrict__ w,
    const float* __restrict__ b, float* __restrict__ out) {
  int gph = blockIdx.x;
  int c = threadIdx.x;
  float v = pooled[gph * H + c] * w[c];
#pragma unroll
  for (int off = 32; off > 0; off >>= 1) v += __shfl_xor(v, off, 64);
  if (c == 0) out[gph] = v + b[0];
}

extern "C" void kernel_launch(void* const* d_in, const int* in_sizes, int n_in,
                              void* d_out, int out_size, void* d_ws, size_t ws_size,
                              hipStream_t stream) {
  const float* x       = (const float*)d_in[0];
  const int*   ei_edge = (const int*)d_in[1];
  const int*   ei_sub  = (const int*)d_in[2];
  const int*   ei_ns   = (const int*)d_in[3];
  const int*   ei_sn   = (const int*)d_in[4];
  const int*   batch   = (const int*)d_in[7];
  const float* emb_w   = (const float*)d_in[8];
  const float* emb_b   = (const float*)d_in[9];
  const float* conv_wl = (const float*)d_in[10];
  const float* conv_bl = (const float*)d_in[11];
  const float* conv_wr = (const float*)d_in[12];
  const float* ln_g    = (const float*)d_in[13];
  const float* ln_b    = (const float*)d_in[14];
  const float* out_w   = (const float*)d_in[15];
  const float* out_b   = (const float*)d_in[16];
  float* out = (float*)d_out;

  const size_t HB = (size_t)N_NODES * H * sizeof(float);   // 25.6 MB
  char* ws = (char*)d_ws;
  float* h      = (float*)(ws);                        // fp32, ground, j==3
  float* h0     = (float*)(ws + HB);                   // fp32 residual (ground)
  unsigned short* ab = (unsigned short*)(ws + 2 * HB); // [node][128] bf16 25.6MB
  // Persistent build outputs:
  int*   deg4   = (int*)(ws + 3 * HB);                           // 1.6 MB
  int*   S      = (int*)(ws + 78400000);                         // 1.6 MB
  int*   bcnt   = (int*)(ws + 92800000);
  int*   boff   = (int*)(ws + 92800512);
  int*   bcur   = (int*)(ws + 92801024);
  int*   blist  = (int*)(ws + 92801536);                         // 1.6 MB
  float* pooled = (float*)(ws + 94401536);                       // 32 KB
  unsigned short* wbt = (unsigned short*)(ws + 94434304);        // 1.38 MB
  int*   tdesc  = (int*)(ws + 95810560);                         // 25.6 KB
  int*   ntiles = (int*)(ws + 95836160);                         // 16 B
  unsigned short* ewbt = (unsigned short*)(ws + 95836608);       // 4 KB
  int*   bincur = (int*)(ws + 95841024);                         // 2 KB
  // Fixed-capacity bin regions (ws_size ~= 256 MiB, plenty of headroom):
  unsigned* binned = (unsigned*)(ws + 100000000);                // 16.8 MB
  int*   slots  = (int*)(ws + 117000000);                        // 16.8 MB

  const int* e0 = ei_edge, *e1 = ei_ns, *e2 = ei_sub, *e3 = ei_sn;

  // --- build + embedding (fused independent branches) ---
  prep_kernel<<<WCONV_BLOCKS + EMB_BLOCKS, 256, 0, stream>>>(
      conv_wl, conv_wr, emb_w, wbt, ewbt, bincur, bcnt,
      x, emb_b, h0, ab, pooled);
  p3_binscatter<<<NBINS, 1024, 0, stream>>>(e0, e1, e2, e3, bincur, binned);
  p46_kernel<<<NBINS, 1024, 0, stream>>>(binned, bincur, deg4, S, slots, bcnt);
  bucket_scan<<<1, 128, 0, stream>>>(bcnt, boff, bcur, ntiles, tdesc);
  bucket_fill<<<dim3((N_NODES + 255) / 256, 4), 256, 0, stream>>>(deg4, bcur, blist);

  // --- network (self half ping-pongs 64 -> 0 -> 64 -> 0 -> h) ---
  for (int j = 0; j < 4; ++j) {
    conv_kernel<<<MAX_TILES, 256, 0, stream>>>(
        h, ab, S + j * N_NODES, deg4 + j * N_NODES, slots,
        blist, tdesc, ntiles, wbt,
        conv_bl + (size_t)j * 21 * H, j,
        (j & 1) ? 0 : 64,          // inoff
        j < 3 ? 1 : 0, j == 3 ? 1 : 0);
  }

  ln_pool_kernel<<<POOL_BLOCKS, 1024, 0, stream>>>(h, h0, ln_g, ln_b, batch, pooled);
  out_kernel<<<NUM_GRAPHS, 64, 0, stream>>>(pooled, out_w, out_b, out);
}

// Round 8
// 333.869 us; speedup vs baseline: 1.1458x; 1.1458x over previous
//
#include <hip/hip_runtime.h>

#define N_NODES 100000
#define G_NODES 50000
#define N_EDGES 800000
#define H 64
#define F_IN 32
#define MAX_DEG 20
#define NUM_GRAPHS 128
#define LN_EPS 1e-5f
#define POOL_BLOCKS 256
#define MAX_TILES 1600

// Binned CSR build: 512 bins over the 4*N key space, FIXED 8192-entry
// capacity per bin (mean 6250, sigma~79 -> +24 sigma, unreachable).
#define NBINS 512
#define BPB 782            // keys per bin: 782*512 = 400384 >= 400000
#define BINCAP_LOG 13      // 8192 entries per bin
#define BINCAP 8192
#define CHUNK 6250         // edges per build block: 6250*512 = 3.2M
#define MKEYS (4 * N_NODES)
#define MEDGES (4 * N_EDGES)

typedef __attribute__((ext_vector_type(8))) short short8;
typedef __attribute__((ext_vector_type(4))) float float4v;

// bf16 helpers (RNE), no header dependency
static __device__ __forceinline__ unsigned short f2b(float f) {
  unsigned u = __float_as_uint(f);
  return (unsigned short)((u + 0x7fffu + ((u >> 16) & 1u)) >> 16);
}
static __device__ __forceinline__ float b2f(unsigned short b) {
  return __uint_as_float(((unsigned)b) << 16);
}

// ---------------- weight preconvert + cursor/bcnt init (runs FIRST) ---------
__global__ __launch_bounds__(256) void wconv_kernel(
    const float* __restrict__ wl, const float* __restrict__ wr,
    const float* __restrict__ ew, unsigned short* __restrict__ wbt,
    unsigned short* __restrict__ ewbt, int* __restrict__ bincur,
    int* __restrict__ bcnt) {
  int i = blockIdx.x * 256 + threadIdx.x;
  if (blockIdx.x == 0) {
    for (int k = threadIdx.x; k < NBINS; k += 256) bincur[k] = k << BINCAP_LOG;
    if (threadIdx.x < 84) bcnt[threadIdx.x] = 0;
  }
  if (i < 84 * 64 * 128) {
    int k = i & 127;
    int ch = (i >> 7) & 63;
    int jb = i >> 13;
    float v = (k < 64) ? wl[jb * 4096 + k * 64 + ch]
                       : wr[jb * 4096 + (k - 64) * 64 + ch];
    wbt[i] = f2b(v);
  } else if (i < 84 * 64 * 128 + H * F_IN) {
    int ii = i - 84 * 64 * 128;
    int c = ii >> 5, f = ii & 31;
    ewbt[ii] = f2b(ew[f * H + c]);
  }
}

// ---------------- MFMA embedding + pooled zero-init -------------------------
__global__ __launch_bounds__(256) void emb_kernel(
    const float* __restrict__ x, const unsigned short* __restrict__ ewbt,
    const float* __restrict__ eb, float* __restrict__ h0,
    unsigned short* __restrict__ ab, float* __restrict__ pooled) {
  int tid = threadIdx.x;
  if (blockIdx.x == 0) {
    for (int i = tid; i < NUM_GRAPHS * H; i += 256) pooled[i] = 0.f;
  }
  int base = blockIdx.x * 64;
  int nIn = min(64, N_NODES - base);
  int qw = tid >> 6, lane = tid & 63;
  __shared__ unsigned short aL[64 * 40];  // stride 40 breaks pow2 banks
  __shared__ float outF[64 * 68];

  {
    int node = tid >> 2, chb = (tid & 3) * 8;
    unsigned short v8[8];
    if (node < nIn) {
      const float* xr = x + ((size_t)(base + node)) * F_IN + chb;
      float4 f0 = *(const float4*)(xr);
      float4 f1 = *(const float4*)(xr + 4);
      v8[0] = f2b(f0.x); v8[1] = f2b(f0.y); v8[2] = f2b(f0.z); v8[3] = f2b(f0.w);
      v8[4] = f2b(f1.x); v8[5] = f2b(f1.y); v8[6] = f2b(f1.z); v8[7] = f2b(f1.w);
    } else {
#pragma unroll
      for (int i = 0; i < 8; ++i) v8[i] = 0;
    }
    *(short8*)&aL[(tid >> 2) * 40 + chb] = *(short8*)v8;
  }
  // no __syncthreads: wave qw staged exactly rows [qw*16, qw*16+16)

  int m = lane & 15, quad = lane >> 4;
  short8 a = *(const short8*)&aL[(qw * 16 + m) * 40 + quad * 8];
  float4v acc[4];
#pragma unroll
  for (int t = 0; t < 4; ++t) {
    float bv = eb[t * 16 + m];
    acc[t] = (float4v){bv, bv, bv, bv};
  }
#pragma unroll
  for (int t = 0; t < 4; ++t) {
    short8 bf = *(const short8*)&ewbt[(t * 16 + m) * F_IN + quad * 8];
    acc[t] = __builtin_amdgcn_mfma_f32_16x16x32_bf16(a, bf, acc[t], 0, 0, 0);
  }
#pragma unroll
  for (int t = 0; t < 4; ++t)
#pragma unroll
    for (int r = 0; r < 4; ++r)
      outF[(qw * 16 + quad * 4 + r) * 68 + t * 16 + m] = acc[t][r];
  for (int r = qw * 16; r < qw * 16 + 16; ++r) {
    if (r < nIn) {
      int node = base + r;
      float v = outF[r * 68 + lane];
      if (node < G_NODES) h0[node * H + lane] = v;
      ab[node * 128 + 64 + lane] = f2b(v);
    }
  }
}

// ---------------- single-pass binning + LDS bin-sort (R5) -------------------
__global__ __launch_bounds__(1024) void p3_binscatter(
    const int* __restrict__ e0, const int* __restrict__ e1,
    const int* __restrict__ e2, const int* __restrict__ e3,
    int* __restrict__ bincur, unsigned* __restrict__ binned) {
  __shared__ int hist[NBINS];
  __shared__ int loff[NBINS];
  __shared__ int gcur[NBINS];
  __shared__ int lcur[NBINS];
  __shared__ int wtot[16];
  __shared__ int lmeta[CHUNK];            // (bin<<10)|keymod per edge, 25 KB
  __shared__ unsigned sbuf[CHUNK];        // staged values, 25 KB
  __shared__ unsigned short sbin[CHUNK];  // bin per staged entry, 12.5 KB
  int t = threadIdx.x, b = blockIdx.x;
  for (int i = t; i < NBINS; i += 1024) hist[i] = 0;
  __syncthreads();
  int j = b >> 7;
  const int* ei = (j == 0) ? e0 : (j == 1) ? e1 : (j == 2) ? e2 : e3;
  int ebase = (b & 127) * CHUNK;
  for (int i = t; i < CHUNK; i += 1024) {
    int dst = ei[N_EDGES + ebase + i];
    int key = j * N_NODES + dst;
    int bin = key / BPB;                  // magic-mul
    lmeta[i] = (bin << 10) | (key - bin * BPB);
    atomicAdd(&hist[bin], 1);
  }
  __syncthreads();
  // exclusive scan over 512 bins (waves 0..7)
  int v = (t < NBINS) ? hist[t] : 0;
  int incl = v;
#pragma unroll
  for (int off = 1; off < 64; off <<= 1) {
    int y = __shfl_up(incl, off, 64);
    if ((t & 63) >= off) incl += y;
  }
  if (t < NBINS && (t & 63) == 63) wtot[t >> 6] = incl;
  __syncthreads();
  if (t < NBINS) {
    int wbase = 0;
    for (int w = 0; w < (t >> 6); ++w) wbase += wtot[w];
    int ex = wbase + incl - v;
    loff[t] = ex;
    lcur[t] = ex;
    gcur[t] = v ? atomicAdd(&bincur[t], v) : 0;
  }
  __syncthreads();
  for (int i = t; i < CHUNK; i += 1024) {
    int src = ei[ebase + i];
    int m = lmeta[i];
    int bin = m >> 10;
    int pos = atomicAdd(&lcur[bin], 1);
    sbuf[pos] = ((unsigned)(m & 1023) << 17) | (unsigned)src;
    sbin[pos] = (unsigned short)bin;
  }
  __syncthreads();
  for (int i = t; i < CHUNK; i += 1024) {
    int bb = sbin[i];
    binned[gcur[bb] + (i - loff[bb])] = sbuf[i];
  }
}

// p46: per bin, fused deg4 + bucket-hist + local CSR scan + slot scatter.
// R4: slot scatter staged in LDS, dense flush. R5: input staged in LDS too.
__global__ __launch_bounds__(1024) void p46_kernel(
    const unsigned* __restrict__ binned, const int* __restrict__ bincur,
    int* __restrict__ deg4, int* __restrict__ S, int* __restrict__ slots,
    int* __restrict__ bcnt) {
  __shared__ int hist[BPB];
  __shared__ int cur[BPB];
  __shared__ int bh[84];
  __shared__ int wtot[16];
  __shared__ unsigned bufin[BINCAP];   // 32 KB input staging
  __shared__ int bufout[BINCAP];       // 32 KB slot staging
  int t = threadIdx.x, bin = blockIdx.x;
  int kb = bin * BPB;
  for (int i = t; i < BPB; i += 1024) hist[i] = 0;
  if (t < 84) bh[t] = 0;
  __syncthreads();
  int start = bin << BINCAP_LOG;
  int end = bincur[bin];
  int n = end - start;
  for (int i = t; i < n; i += 1024) {
    unsigned v = binned[start + i];
    bufin[i] = v;
    atomicAdd(&hist[v >> 17], 1);
  }
  __syncthreads();
  for (int i = t; i < BPB; i += 1024) {
    int key = kb + i;
    if (key < MKEYS) {
      int d = hist[i];
      deg4[key] = d;
      int j = key / N_NODES;
      int b = d < MAX_DEG ? d : MAX_DEG;
      atomicAdd(&bh[j * 21 + b], 1);
    }
  }
  int base = t * 4;
  int v0 = 0, v1 = 0, v2 = 0, v3 = 0;
  if (base < BPB) {
    v0 = hist[base];
    v1 = (base + 1 < BPB) ? hist[base + 1] : 0;
    v2 = (base + 2 < BPB) ? hist[base + 2] : 0;
    v3 = (base + 3 < BPB) ? hist[base + 3] : 0;
  }
  int s = v0 + v1 + v2 + v3;
  int incl = s;
#pragma unroll
  for (int off = 1; off < 64; off <<= 1) {
    int y = __shfl_up(incl, off, 64);
    if ((t & 63) >= off) incl += y;
  }
  if ((t & 63) == 63) wtot[t >> 6] = incl;
  __syncthreads();
  int wbase = 0;
  for (int w = 0; w < (t >> 6); ++w) wbase += wtot[w];
  int ex = wbase + incl - s;           // bin-LOCAL exclusive prefix
  if (base < BPB) {
    cur[base] = ex;
    if (base + 1 < BPB) cur[base + 1] = ex + v0;
    if (base + 2 < BPB) cur[base + 2] = ex + v0 + v1;
    if (base + 3 < BPB) cur[base + 3] = ex + v0 + v1 + v2;
  }
  __syncthreads();
  for (int i = t; i < BPB; i += 1024)
    if (kb + i < MKEYS) S[kb + i] = start + cur[i];
  if (t < 84 && bh[t]) atomicAdd(&bcnt[t], bh[t]);
  __syncthreads();
  for (int i = t; i < n; i += 1024) {
    unsigned v = bufin[i];
    int pos = atomicAdd(&cur[v >> 17], 1);   // LDS scatter (bin-local pos)
    bufout[pos] = (int)(v & 0x1ffffu);
  }
  __syncthreads();
  for (int i = t; i < n; i += 1024) slots[start + i] = bufout[i];  // dense flush
}

// ---------------- bucket scan + tile descriptors (one block) ----------------
__global__ __launch_bounds__(128) void bucket_scan(
    const int* __restrict__ bcnt, int* __restrict__ boff, int* __restrict__ bcur,
    int* __restrict__ ntiles, int* __restrict__ tdesc) {
  __shared__ int wt[2];
  __shared__ int exL[84], cntL[84], toffL[84];
  int t = threadIdx.x;
  int v = (t < 84) ? bcnt[t] : 0;
  int incl = v;
#pragma unroll
  for (int off = 1; off < 64; off <<= 1) {
    int y = __shfl_up(incl, off, 64);
    if ((t & 63) >= off) incl += y;
  }
  if ((t & 63) == 63) wt[t >> 6] = incl;
  __syncthreads();
  int wbase = (t >> 6) ? wt[0] : 0;
  if (t < 84) {
    int ex = wbase + incl - v;
    boff[t] = ex;
    bcur[t] = ex;
    exL[t] = ex;
    cntL[t] = v;
  }
  __syncthreads();
  if (t < 4) {
    int acc = 0;
    for (int bb = 0; bb < 21; ++bb) {
      toffL[t * 21 + bb] = acc;
      acc += (cntL[t * 21 + bb] + 63) >> 6;
    }
    ntiles[t] = acc;
  }
  __syncthreads();
  for (int jb = 0; jb < 84; ++jb) {
    int j = jb / 21, b = jb - j * 21;
    int cnt = cntL[jb], off = exL[jb], tb = toffL[jb];
    int nt = (cnt + 63) >> 6;
    for (int i = t; i < nt; i += 128) {
      int s2 = i << 6;
      int nIn = min(64, cnt - s2);
      tdesc[j * MAX_TILES + tb + i] = ((off + s2) << 12) | (b << 7) | nIn;
    }
  }
}

__global__ __launch_bounds__(256) void bucket_fill(
    const int* __restrict__ deg4, int* __restrict__ bcur, int* __restrict__ blist) {
  __shared__ int hist[21];
  __shared__ int base[21];
  int t = threadIdx.x;
  if (t < 21) hist[t] = 0;
  __syncthreads();
  int node = blockIdx.x * 256 + t;
  int j = blockIdx.y;
  int b = 0, lpos = 0;
  bool valid = (node < N_NODES);
  if (valid) {
    int d = deg4[j * N_NODES + node];
    b = d < MAX_DEG ? d : MAX_DEG;
    lpos = atomicAdd(&hist[b], 1);
  }
  __syncthreads();
  if (t < 21 && hist[t]) base[t] = atomicAdd(&bcur[j * 21 + t], hist[t]);
  __syncthreads();
  if (valid) blist[base[b] + lpos] = node;
}

// ---------------- FUSED conv: lane-per-row-slice gather + MFMA --------------
// R2: gather is lane-per-row-slice: row = tid>>2, each lane owns 16 channels
// (32B) of ONE row. All 64 rows gather concurrently; latency rounds per tile
// = ceil(deg/4). 8x16B loads in flight per lane. (R7 lesson: unroll 8 raised
// VGPR pressure for marginal deg>=8 benefit -> keep 4.)
__global__ __launch_bounds__(256) void conv_kernel(
    float* __restrict__ h, unsigned short* __restrict__ ab,
    const int* __restrict__ S, const int* __restrict__ deg,
    const int* __restrict__ slots,
    const int* __restrict__ blist, const int* __restrict__ tdesc,
    const int* __restrict__ ntiles, const unsigned short* __restrict__ wbt,
    const float* __restrict__ bl, int j, int inoff, int do_relu, int last) {
  if ((int)blockIdx.x >= ntiles[j]) return;
  int d = tdesc[j * MAX_TILES + blockIdx.x];
  int nIn = d & 127;
  int b = (d >> 7) & 31;
  const int* lst = blist + (d >> 12);
  int outoff = 64 - inoff;

  int tid = threadIdx.x;
  int qw = tid >> 6, lane = tid & 63;

  if (b == 0) {
    for (int r = qw * 16; r < qw * 16 + 16; ++r) {
      if (r < nIn) {
        int node = lst[r];
        float v = b2f(ab[node * 128 + inoff + lane]);
        if (do_relu) v = fmaxf(v, 0.f);
        if (last) {
          if (node < G_NODES) h[node * H + lane] = v;
        } else {
          ab[node * 128 + outoff + lane] = f2b(v);
        }
      }
    }
    return;
  }

  __shared__ unsigned short aL[64 * 136];  // 17408 B; reused as fp32[64*68]
  __shared__ int nodeS[64];

  {
    int r = tid >> 2;            // row 0..63 (wave qw owns rows qw*16..+15)
    int cb = (tid & 3) * 16;     // 16-channel slice (32B) within the row
    bool act = (r < nIn);
    int node = act ? lst[r] : 0;
    if ((tid & 3) == 0 && act) nodeS[r] = node;

    float acc[16];
#pragma unroll
    for (int k = 0; k < 16; ++k) acc[k] = 0.f;
    uint4 selfA = make_uint4(0u, 0u, 0u, 0u);
    uint4 selfB = make_uint4(0u, 0u, 0u, 0u);

#define ACC8(v, kb)                                                      \
  acc[kb + 0] += b2f((unsigned short)(v).x);                             \
  acc[kb + 1] += b2f((unsigned short)((v).x >> 16));                     \
  acc[kb + 2] += b2f((unsigned short)(v).y);                             \
  acc[kb + 3] += b2f((unsigned short)((v).y >> 16));                     \
  acc[kb + 4] += b2f((unsigned short)(v).z);                             \
  acc[kb + 5] += b2f((unsigned short)((v).z >> 16));                     \
  acc[kb + 6] += b2f((unsigned short)(v).w);                             \
  acc[kb + 7] += b2f((unsigned short)((v).w >> 16));

    if (act) {
      const unsigned short* abb = ab + inoff + cb;
      selfA = *(const uint4*)&abb[node * 128];
      selfB = *(const uint4*)&abb[node * 128 + 8];
      int off = S[node];
      int dg = (b < MAX_DEG) ? b : deg[node];
      int e = 0;
      for (; e + 3 < dg; e += 4) {
        int n0 = slots[off + e];
        int n1 = slots[off + e + 1];
        int n2 = slots[off + e + 2];
        int n3 = slots[off + e + 3];
        uint4 a0 = *(const uint4*)&abb[n0 * 128];
        uint4 b0 = *(const uint4*)&abb[n0 * 128 + 8];
        uint4 a1 = *(const uint4*)&abb[n1 * 128];
        uint4 b1 = *(const uint4*)&abb[n1 * 128 + 8];
        uint4 a2 = *(const uint4*)&abb[n2 * 128];
        uint4 b2 = *(const uint4*)&abb[n2 * 128 + 8];
        uint4 a3 = *(const uint4*)&abb[n3 * 128];
        uint4 b3 = *(const uint4*)&abb[n3 * 128 + 8];
        ACC8(a0, 0) ACC8(b0, 8)
        ACC8(a1, 0) ACC8(b1, 8)
        ACC8(a2, 0) ACC8(b2, 8)
        ACC8(a3, 0) ACC8(b3, 8)
      }
      int rem = dg - e;
      if (rem > 0) {
        int n0 = slots[off + e];
        int n1 = (rem > 1) ? slots[off + e + 1] : n0;
        int n2 = (rem > 2) ? slots[off + e + 2] : n0;
        uint4 a0 = *(const uint4*)&abb[n0 * 128];
        uint4 b0 = *(const uint4*)&abb[n0 * 128 + 8];
        uint4 a1 = *(const uint4*)&abb[n1 * 128];
        uint4 b1 = *(const uint4*)&abb[n1 * 128 + 8];
        uint4 a2 = *(const uint4*)&abb[n2 * 128];
        uint4 b2 = *(const uint4*)&abb[n2 * 128 + 8];
        ACC8(a0, 0) ACC8(b0, 8)
        if (rem > 1) { ACC8(a1, 0) ACC8(b1, 8) }
        if (rem > 2) { ACC8(a2, 0) ACC8(b2, 8) }
      }
    }
#undef ACC8

    unsigned p0 = (unsigned)f2b(acc[0]) | ((unsigned)f2b(acc[1]) << 16);
    unsigned p1 = (unsigned)f2b(acc[2]) | ((unsigned)f2b(acc[3]) << 16);
    unsigned p2 = (unsigned)f2b(acc[4]) | ((unsigned)f2b(acc[5]) << 16);
    unsigned p3 = (unsigned)f2b(acc[6]) | ((unsigned)f2b(acc[7]) << 16);
    unsigned p4 = (unsigned)f2b(acc[8]) | ((unsigned)f2b(acc[9]) << 16);
    unsigned p5 = (unsigned)f2b(acc[10]) | ((unsigned)f2b(acc[11]) << 16);
    unsigned p6 = (unsigned)f2b(acc[12]) | ((unsigned)f2b(acc[13]) << 16);
    unsigned p7 = (unsigned)f2b(acc[14]) | ((unsigned)f2b(acc[15]) << 16);
    *(uint4*)&aL[r * 136 + cb] = make_uint4(p0, p1, p2, p3);       // hsum k 0:64
    *(uint4*)&aL[r * 136 + cb + 8] = make_uint4(p4, p5, p6, p7);
    *(uint4*)&aL[r * 136 + 64 + cb] = selfA;                       // self k 64:128
    *(uint4*)&aL[r * 136 + 64 + cb + 8] = selfB;
  }
  // no barrier: wave wrote exactly rows [qw*16, qw*16+16) and reads only those

  int m = lane & 15, quad = lane >> 4;
  const unsigned short* wbase = wbt + (size_t)(j * 21 + b) * 64 * 128;
  float4v acc[4];
#pragma unroll
  for (int t = 0; t < 4; ++t) {
    float bv = bl[b * 64 + t * 16 + m];
    acc[t] = (float4v){bv, bv, bv, bv};
  }
#pragma unroll
  for (int ks = 0; ks < 4; ++ks) {
    short8 a = *(const short8*)&aL[(qw * 16 + m) * 136 + ks * 32 + quad * 8];
#pragma unroll
    for (int t = 0; t < 4; ++t) {
      short8 bf = *(const short8*)&wbase[(t * 16 + m) * 128 + ks * 32 + quad * 8];
      acc[t] = __builtin_amdgcn_mfma_f32_16x16x32_bf16(a, bf, acc[t], 0, 0, 0);
    }
  }
  if (do_relu) {
#pragma unroll
    for (int t = 0; t < 4; ++t)
#pragma unroll
      for (int r = 0; r < 4; ++r) acc[t][r] = fmaxf(acc[t][r], 0.f);
  }
  float* outF = (float*)aL;
#pragma unroll
  for (int t = 0; t < 4; ++t)
#pragma unroll
    for (int r = 0; r < 4; ++r)
      outF[(qw * 16 + quad * 4 + r) * 68 + t * 16 + m] = acc[t][r];
  if (last) {
    for (int r = qw * 16; r < qw * 16 + 16; ++r)
      if (r < nIn && nodeS[r] < G_NODES)
        h[nodeS[r] * H + lane] = outF[r * 68 + lane];
  } else {
    for (int r = qw * 16; r < qw * 16 + 16; ++r)
      if (r < nIn) ab[nodeS[r] * 128 + outoff + lane] = f2b(outF[r * 68 + lane]);
  }
}

// ---------------- fused layernorm + residual + ground-node pool -------------
// R7 lessons: POOL_BLOCKS=96 starved parallelism (64us, 16% occ) -> back to
// 256. R8: latency-bound fix per counters (VALU 4%, HBM 3%): process 4 nodes
// per wave iteration (8 h/h0 loads in flight) + fused sum/sumsq butterfly
// (var = E[v^2]-mu^2) -> 4x fewer latency rounds, 4-way ILP in reduction.
__global__ __launch_bounds__(1024) void ln_pool_kernel(
    const float* __restrict__ h, const float* __restrict__ h0,
    const float* __restrict__ g, const float* __restrict__ b,
    const int* __restrict__ batch, float* __restrict__ pooled) {
  __shared__ float sm[NUM_GRAPHS * H];  // 32 KB
  int t = threadIdx.x;
  for (int i = t; i < NUM_GRAPHS * H; i += 1024) sm[i] = 0.f;
  __syncthreads();
  int lane = t & 63, w = t >> 6;  // 16 waves
  float gl = g[lane], bl_ = b[lane];
  const int per = (G_NODES + POOL_BLOCKS - 1) / POOL_BLOCKS;
  int start = blockIdx.x * per;
  int end = min(start + per, G_NODES);
  for (int n0 = start + w; n0 < end; n0 += 64) {
    int n1 = n0 + 16, n2 = n0 + 32, n3 = n0 + 48;
    bool a1 = n1 < end, a2 = n2 < end, a3 = n3 < end;
    // issue all loads up front (8 vector + 4 scalar in flight)
    float v0 = h[n0 * H + lane];
    float v1 = a1 ? h[n1 * H + lane] : 0.f;
    float v2 = a2 ? h[n2 * H + lane] : 0.f;
    float v3 = a3 ? h[n3 * H + lane] : 0.f;
    float r0 = h0[n0 * H + lane];
    float r1 = a1 ? h0[n1 * H + lane] : 0.f;
    float r2 = a2 ? h0[n2 * H + lane] : 0.f;
    float r3 = a3 ? h0[n3 * H + lane] : 0.f;
    int b0 = batch[n0];
    int b1 = a1 ? batch[n1] : 0;
    int b2 = a2 ? batch[n2] : 0;
    int b3 = a3 ? batch[n3] : 0;
    float s0 = v0, q0 = v0 * v0;
    float s1 = v1, q1 = v1 * v1;
    float s2 = v2, q2 = v2 * v2;
    float s3 = v3, q3 = v3 * v3;
#pragma unroll
    for (int off = 32; off > 0; off >>= 1) {
      s0 += __shfl_xor(s0, off, 64); q0 += __shfl_xor(q0, off, 64);
      s1 += __shfl_xor(s1, off, 64); q1 += __shfl_xor(q1, off, 64);
      s2 += __shfl_xor(s2, off, 64); q2 += __shfl_xor(q2, off, 64);
      s3 += __shfl_xor(s3, off, 64); q3 += __shfl_xor(q3, off, 64);
    }
    float mu0 = s0 * (1.0f / H), mu1 = s1 * (1.0f / H);
    float mu2 = s2 * (1.0f / H), mu3 = s3 * (1.0f / H);
    float i0 = rsqrtf(fmaxf(q0 * (1.0f / H) - mu0 * mu0, 0.f) + LN_EPS);
    float i1 = rsqrtf(fmaxf(q1 * (1.0f / H) - mu1 * mu1, 0.f) + LN_EPS);
    float i2 = rsqrtf(fmaxf(q2 * (1.0f / H) - mu2 * mu2, 0.f) + LN_EPS);
    float i3 = rsqrtf(fmaxf(q3 * (1.0f / H) - mu3 * mu3, 0.f) + LN_EPS);
    atomicAdd(&sm[b0 * H + lane], (v0 - mu0) * i0 * gl + bl_ + r0);
    if (a1) atomicAdd(&sm[b1 * H + lane], (v1 - mu1) * i1 * gl + bl_ + r1);
    if (a2) atomicAdd(&sm[b2 * H + lane], (v2 - mu2) * i2 * gl + bl_ + r2);
    if (a3) atomicAdd(&sm[b3 * H + lane], (v3 - mu3) * i3 * gl + bl_ + r3);
  }
  __syncthreads();
  for (int i = t; i < NUM_GRAPHS * H; i += 1024) {
    float v = sm[i];
    if (v != 0.f) atomicAdd(&pooled[i], v);
  }
}

__global__ __launch_bounds__(64) void out_kernel(
    const float* __restrict__ pooled, const float* __restrict__ w,
    const float* __restrict__ b, float* __restrict__ out) {
  int gph = blockIdx.x;
  int c = threadIdx.x;
  float v = pooled[gph * H + c] * w[c];
#pragma unroll
  for (int off = 32; off > 0; off >>= 1) v += __shfl_xor(v, off, 64);
  if (c == 0) out[gph] = v + b[0];
}

extern "C" void kernel_launch(void* const* d_in, const int* in_sizes, int n_in,
                              void* d_out, int out_size, void* d_ws, size_t ws_size,
                              hipStream_t stream) {
  const float* x       = (const float*)d_in[0];
  const int*   ei_edge = (const int*)d_in[1];
  const int*   ei_sub  = (const int*)d_in[2];
  const int*   ei_ns   = (const int*)d_in[3];
  const int*   ei_sn   = (const int*)d_in[4];
  const int*   batch   = (const int*)d_in[7];
  const float* emb_w   = (const float*)d_in[8];
  const float* emb_b   = (const float*)d_in[9];
  const float* conv_wl = (const float*)d_in[10];
  const float* conv_bl = (const float*)d_in[11];
  const float* conv_wr = (const float*)d_in[12];
  const float* ln_g    = (const float*)d_in[13];
  const float* ln_b    = (const float*)d_in[14];
  const float* out_w   = (const float*)d_in[15];
  const float* out_b   = (const float*)d_in[16];
  float* out = (float*)d_out;

  const size_t HB = (size_t)N_NODES * H * sizeof(float);   // 25.6 MB
  char* ws = (char*)d_ws;
  float* h      = (float*)(ws);                        // fp32, ground, j==3
  float* h0     = (float*)(ws + HB);                   // fp32 residual (ground)
  unsigned short* ab = (unsigned short*)(ws + 2 * HB); // [node][128] bf16 25.6MB
  // Persistent build outputs:
  int*   deg4   = (int*)(ws + 3 * HB);                           // 1.6 MB
  int*   S      = (int*)(ws + 78400000);                         // 1.6 MB
  int*   bcnt   = (int*)(ws + 92800000);
  int*   boff   = (int*)(ws + 92800512);
  int*   bcur   = (int*)(ws + 92801024);
  int*   blist  = (int*)(ws + 92801536);                         // 1.6 MB
  float* pooled = (float*)(ws + 94401536);                       // 32 KB
  unsigned short* wbt = (unsigned short*)(ws + 94434304);        // 1.38 MB
  int*   tdesc  = (int*)(ws + 95810560);                         // 25.6 KB
  int*   ntiles = (int*)(ws + 95836160);                         // 16 B
  unsigned short* ewbt = (unsigned short*)(ws + 95836608);       // 4 KB
  int*   bincur = (int*)(ws + 95841024);                         // 2 KB
  // Fixed-capacity bin regions (ws_size ~= 256 MiB, plenty of headroom):
  unsigned* binned = (unsigned*)(ws + 100000000);                // 16.8 MB
  int*   slots  = (int*)(ws + 117000000);                        // 16.8 MB

  const int* e0 = ei_edge, *e1 = ei_ns, *e2 = ei_sub, *e3 = ei_sn;

  // --- build ---
  wconv_kernel<<<(84 * 64 * 128 + H * F_IN + 255) / 256, 256, 0, stream>>>(
      conv_wl, conv_wr, emb_w, wbt, ewbt, bincur, bcnt);
  p3_binscatter<<<NBINS, 1024, 0, stream>>>(e0, e1, e2, e3, bincur, binned);
  p46_kernel<<<NBINS, 1024, 0, stream>>>(binned, bincur, deg4, S, slots, bcnt);
  bucket_scan<<<1, 128, 0, stream>>>(bcnt, boff, bcur, ntiles, tdesc);
  bucket_fill<<<dim3((N_NODES + 255) / 256, 4), 256, 0, stream>>>(deg4, bcur, blist);

  // --- network (self half ping-pongs 64 -> 0 -> 64 -> 0 -> h) ---
  emb_kernel<<<(N_NODES + 63) / 64, 256, 0, stream>>>(x, ewbt, emb_b, h0, ab, pooled);

  for (int j = 0; j < 4; ++j) {
    conv_kernel<<<MAX_TILES, 256, 0, stream>>>(
        h, ab, S + j * N_NODES, deg4 + j * N_NODES, slots,
        blist, tdesc, ntiles, wbt,
        conv_bl + (size_t)j * 21 * H, j,
        (j & 1) ? 0 : 64,          // inoff
        j < 3 ? 1 : 0, j == 3 ? 1 : 0);
  }

  ln_pool_kernel<<<POOL_BLOCKS, 1024, 0, stream>>>(h, h0, ln_g, ln_b, batch, pooled);
  out_kernel<<<NUM_GRAPHS, 64, 0, stream>>>(pooled, out_w, out_b, out);
}